// Round 1
// 625.605 us; speedup vs baseline: 1.0085x; 1.0085x over previous
//
#include <hip/hip_runtime.h>

#define NBATCH 32
#define QH 32
#define KVH 8
#define G 4
#define DH 128
#define BS 128
#define NB 512
#define CONST_VAL 10.0f
#define EPS_T 1.1754943508222875e-38f
#define SCALE_F 0.08838834764831845f

// ws layout (floats):
//   partial: NB*KVH*G*DH  = 2,097,152
//   bsum:    NB*KVH*G     = 16,384
//   S:       NBATCH*KVH*G = 1,024
//   den:     NB*KVH*G     = 16,384

// ---------------- helpers ----------------
__device__ __forceinline__ float4 ld4(const float* __restrict__ p) {
    return *(const float4* __restrict__)p;
}
__device__ __forceinline__ void fma4(float4& o, float a, float4 v) {
    o.x = fmaf(a, v.x, o.x);
    o.y = fmaf(a, v.y, o.y);
    o.z = fmaf(a, v.z, o.z);
    o.w = fmaf(a, v.w, o.w);
}
__device__ __forceinline__ float dot8(float4 a0, float4 a1, float4 b0, float4 b1) {
    float r = a0.x * b0.x;
    r = fmaf(a0.y, b0.y, r);
    r = fmaf(a0.z, b0.z, r);
    r = fmaf(a0.w, b0.w, r);
    r = fmaf(a1.x, b1.x, r);
    r = fmaf(a1.y, b1.y, r);
    r = fmaf(a1.z, b1.z, r);
    r = fmaf(a1.w, b1.w, r);
    return r;
}
// sum across the 4 lane-groups (lanes l, l^16, l^32, l^48)
__device__ __forceinline__ void redcross4(float4& v) {
    v.x += __shfl_xor(v.x, 16); v.y += __shfl_xor(v.y, 16);
    v.z += __shfl_xor(v.z, 16); v.w += __shfl_xor(v.w, 16);
    v.x += __shfl_xor(v.x, 32); v.y += __shfl_xor(v.y, 32);
    v.z += __shfl_xor(v.z, 32); v.w += __shfl_xor(v.w, 32);
}

__global__ void pa_zero_S(float* S) {
    int i = blockIdx.x * 256 + threadIdx.x;
    if (i < NBATCH * KVH * G) S[i] = 0.f;
}

// one fused step: 4 K/V rows (one per 16-lane group), all 4 g heads.
//   lane layout: grp = lane>>4 owns row s = step*4+grp; c = lane&15 owns
//   d-chunks [4c..4c+3] and [64+4c..64+4c+3].  After the 16-lane butterfly
//   every lane of a group holds the full dot -> exp computed redundantly
//   (free: it is exactly the broadcast PV needs).
__device__ __forceinline__ void pa_step(
    int step, int grp, float b_lo, float b_hi,
    float4 k0, float4 k1, float4 v0, float4 v1,
    const float4 (&qlo)[G], const float4 (&qhi)[G],
    float4 (&oLo)[G], float4 (&oHi)[G], float (&es)[G])
{
    float pr[G];
#pragma unroll
    for (int g = 0; g < G; ++g)
        pr[g] = dot8(qlo[g], qhi[g], k0, k1);
#pragma unroll
    for (int g = 0; g < G; ++g) {           // reduce over the 16 lanes of the group
        pr[g] += __shfl_xor(pr[g], 1);
        pr[g] += __shfl_xor(pr[g], 2);
        pr[g] += __shfl_xor(pr[g], 4);
        pr[g] += __shfl_xor(pr[g], 8);
    }
    const int s = step * 4 + grp;
    const float bb = __shfl(step < 16 ? b_lo : b_hi, s & 63);
#pragma unroll
    for (int g = 0; g < G; ++g) {
        float e = __expf(pr[g] + bb - CONST_VAL);
        es[g] += e;
        fma4(oLo[g], e, v0);
        fma4(oHi[g], e, v1);
    }
}

// one wave per (n, kh); zero LDS, zero barriers.  K/V streamed global->VGPR,
// coalesced (16 lanes x 16B = 256B contiguous per row-half per load), with a
// one-step A/B prefetch so loads stay in flight across compute (counted vmcnt,
// never a barrier drain).
__global__ __launch_bounds__(64) void pa_pass1(
    const float* __restrict__ query,       // [B, QH, DH]
    const float* __restrict__ key_cache,   // [NCB, BS, KVH, DH]
    const float* __restrict__ value_cache, // [NCB, BS, KVH, DH]
    const float* __restrict__ mapping,     // [NB, B]
    const float* __restrict__ bias,        // [NB, BS]
    const int*   __restrict__ block_list,  // [NB]
    float* __restrict__ partial,           // [NB, KVH, G, DH]
    float* __restrict__ bsum,              // [NB, KVH, G]
    float* __restrict__ S)                 // [B, KVH, G]
{
    const int n    = blockIdx.x;
    const int kh   = blockIdx.y;
    const int lane = threadIdx.x;   // 0..63
    const int grp  = lane >> 4;     // 0..3 : row within step
    const int c    = lane & 15;     // 0..15: float4 chunk within row

    // mapping row (one-hot in practice; handled generally)
    float w = 0.f;
    if (lane < NBATCH) w = mapping[n * NBATCH + lane];
    const unsigned long long mball = __ballot(w != 0.f);

    float4 qlo[G], qhi[G], oLo[G], oHi[G];
    float  es[G];
#pragma unroll
    for (int g = 0; g < G; ++g) {
        qlo[g] = make_float4(0.f, 0.f, 0.f, 0.f);
        qhi[g] = make_float4(0.f, 0.f, 0.f, 0.f);
        oLo[g] = make_float4(0.f, 0.f, 0.f, 0.f);
        oHi[g] = make_float4(0.f, 0.f, 0.f, 0.f);
        es[g]  = 0.f;
    }

    // q[g][dslice] = sum_b w_b * SCALE * query[b, kh*G+g, dslice]
    unsigned long long mm = mball;
    while (mm) {
        const int b = __ffsll(mm) - 1;
        mm &= mm - 1;
        const float wb = __shfl(w, b) * SCALE_F;
        const float* qr = query + ((size_t)b * QH + (size_t)kh * G) * DH + 4 * c;
#pragma unroll
        for (int g = 0; g < G; ++g) {
            fma4(qlo[g], wb, ld4(qr + g * DH));
            fma4(qhi[g], wb, ld4(qr + g * DH + 64));
        }
    }

    // bias row resident in 2 VGPRs; per-step value fetched via bpermute
    const float b_lo = bias[(size_t)n * BS + lane];
    const float b_hi = bias[(size_t)n * BS + 64 + lane];

    const int p = block_list[n];
    const size_t blk = (size_t)p * BS * KVH * DH + (size_t)kh * DH
                     + (size_t)grp * (KVH * DH) + 4 * c;
    const float* kb = key_cache   + blk;
    const float* vb = value_cache + blk;
    const int SSTRIDE = 4 * KVH * DH;   // 4 rows per step = 4096 floats

    // prologue: load step 0 into A
    float4 kA0 = ld4(kb),      kA1 = ld4(kb + 64);
    float4 vA0 = ld4(vb),      vA1 = ld4(vb + 64);

    for (int it = 0; it < 16; ++it) {
        // prefetch step 2it+1 into B (in flight across STEP A)
        const float* kpB = kb + (size_t)(2 * it + 1) * SSTRIDE;
        const float* vpB = vb + (size_t)(2 * it + 1) * SSTRIDE;
        float4 kB0 = ld4(kpB), kB1 = ld4(kpB + 64);
        float4 vB0 = ld4(vpB), vB1 = ld4(vpB + 64);

        pa_step(2 * it, grp, b_lo, b_hi, kA0, kA1, vA0, vA1,
                qlo, qhi, oLo, oHi, es);

        // prefetch step 2it+2 into A (clamped to a safe address on last iter)
        const int sA = (it < 15) ? (2 * it + 2) : 0;
        const float* kpA = kb + (size_t)sA * SSTRIDE;
        const float* vpA = vb + (size_t)sA * SSTRIDE;
        kA0 = ld4(kpA); kA1 = ld4(kpA + 64);
        vA0 = ld4(vpA); vA1 = ld4(vpA + 64);

        pa_step(2 * it + 1, grp, b_lo, b_hi, kB0, kB1, vB0, vB1,
                qlo, qhi, oLo, oHi, es);
    }

    // combine the 4 s-residue classes (one per group)
#pragma unroll
    for (int g = 0; g < G; ++g) {
        es[g] += __shfl_xor(es[g], 16);
        es[g] += __shfl_xor(es[g], 32);
        redcross4(oLo[g]);
        redcross4(oHi[g]);
    }

    const size_t base = ((size_t)n * KVH + kh) * G;
    if (lane == 0)
        *(float4*)(bsum + base) = make_float4(es[0], es[1], es[2], es[3]);

    if (w != 0.f) {   // one lane per active batch
#pragma unroll
        for (int g = 0; g < G; ++g)
            atomicAdd(&S[(lane * KVH + kh) * G + g], w * es[g]);
    }

    if (lane < 16) {  // lanes 0..15 hold the full reduced output
        const size_t pb = base * DH;
#pragma unroll
        for (int g = 0; g < G; ++g) {
            *(float4*)(partial + pb + (size_t)g * DH + 4 * c)      = oLo[g];
            *(float4*)(partial + pb + (size_t)g * DH + 64 + 4 * c) = oHi[g];
        }
    }
}

// den[n,kh,g] = max(bsum[n,kh,g], sum_b map[n,b]*S[b,kh,g] + EPS)
__global__ __launch_bounds__(256) void pa_den(
    const float* __restrict__ mapping,  // [NB, B]
    const float* __restrict__ bsum,     // [NB, KVH, G]
    const float* __restrict__ S,        // [B, KVH, G]
    float* __restrict__ den)            // [NB, KVH, G]
{
    int i = blockIdx.x * 256 + threadIdx.x;
    if (i >= NB * KVH * G) return;
    int g  = i & (G - 1);
    int kh = (i / G) & (KVH - 1);
    int n  = i / (G * KVH);
    float gs = 0.f;
    for (int b = 0; b < NBATCH; ++b)
        gs += mapping[n * NBATCH + b] * S[(b * KVH + kh) * G + g];
    gs += EPS_T;
    den[i] = fmaxf(bsum[i], gs);
}

__global__ __launch_bounds__(256) void pa_pass2(
    const float* __restrict__ mapping,  // [NB, B]
    const float* __restrict__ partial,  // [NB, KVH, G, DH]
    const float* __restrict__ den,      // [NB, KVH, G]
    float* __restrict__ out)            // [B, QH, DH]
{
    int b  = blockIdx.x;   // 0..31
    int kh = blockIdx.y;   // 0..7
    int t  = threadIdx.x;  // 0..255
    int g  = t >> 7;       // 0..1  (also handles g+2)
    int d  = t & 127;

    __shared__ float sWc[NB];  // mapping column b
    for (int i = t; i < NB; i += 256) sWc[i] = mapping[i * NBATCH + b];
    __syncthreads();

    float a0 = 0.f, a1 = 0.f;
    for (int n = 0; n < NB; ++n) {
        float w = sWc[n];
        if (w == 0.f) continue;
        int di = (n * KVH + kh) * G;
        size_t pb = (size_t)di * DH;
        a0 += w * partial[pb + (size_t)g * DH + d] / den[di + g];
        a1 += w * partial[pb + (size_t)(g + 2) * DH + d] / den[di + g + 2];
    }
    size_t ob = ((size_t)b * QH + (size_t)kh * G) * DH;
    out[ob + (size_t)g * DH + d]       = a0;
    out[ob + (size_t)(g + 2) * DH + d] = a1;
}

extern "C" void kernel_launch(void* const* d_in, const int* in_sizes, int n_in,
                              void* d_out, int out_size, void* d_ws, size_t ws_size,
                              hipStream_t stream) {
    const float* query       = (const float*)d_in[0];
    const float* key_cache   = (const float*)d_in[1];
    const float* value_cache = (const float*)d_in[2];
    const float* mapping     = (const float*)d_in[3];
    const float* bias        = (const float*)d_in[4];
    const int*   block_list  = (const int*)d_in[5];
    float* out = (float*)d_out;

    float* partial = (float*)d_ws;
    float* bsum    = partial + (size_t)NB * KVH * G * DH;
    float* S       = bsum + (size_t)NB * KVH * G;
    float* den     = S + (size_t)NBATCH * KVH * G;

    pa_zero_S<<<4, 256, 0, stream>>>(S);
    pa_pass1<<<dim3(NB, KVH), 64, 0, stream>>>(
        query, key_cache, value_cache, mapping, bias, block_list, partial, bsum, S);
    pa_den<<<(NB * KVH * G + 255) / 256, 256, 0, stream>>>(mapping, bsum, S, den);
    pa_pass2<<<dim3(NBATCH, KVH), 256, 0, stream>>>(mapping, partial, den, out);
}